// Round 8
// baseline (665.261 us; speedup 1.0000x reference)
//
#include <hip/hip_runtime.h>
#include <hip/hip_bf16.h>
#include <math.h>

#define N_NODES 20000
#define N_EDGES 640000
#define ET_EDGES (N_EDGES + N_NODES)   // with self-loops
#define G_GRAPHS 64
#define NEG_SLOPE 0.2f

// ---------------- CSR construction (+ graph bounds folded in) ----------------

__global__ void hist_dst(const int* __restrict__ ei, int* __restrict__ cnt,
                         const int* __restrict__ batch, int* __restrict__ gstart) {
    int j = blockIdx.x * blockDim.x + threadIdx.x;
    if (blockIdx.x == 0 && threadIdx.x <= G_GRAPHS) {
        int g = threadIdx.x;
        int lo = 0, hi = N_NODES;
        while (lo < hi) {              // first i with batch[i] >= g
            int mid = (lo + hi) >> 1;
            if (batch[mid] < g) lo = mid + 1; else hi = mid;
        }
        gstart[g] = lo;
    }
    if (j >= ET_EDGES) return;
    int d = (j < N_EDGES) ? ei[N_EDGES + j] : (j - N_EDGES);
    atomicAdd(&cnt[d], 1);
}

__global__ __launch_bounds__(1024) void scan_rowptr(const int* __restrict__ cnt,
                                                    int* __restrict__ row_ptr) {
    __shared__ int sums[1024];
    const int n = N_NODES;
    const int CH = (n + 1023) / 1024;   // 20
    int t = threadIdx.x;
    int base = t * CH;
    int s = 0;
    for (int i = 0; i < CH; ++i) {
        int idx = base + i;
        if (idx < n) s += cnt[idx];
    }
    sums[t] = s;
    __syncthreads();
    for (int o = 1; o < 1024; o <<= 1) {
        int v = (t >= o) ? sums[t - o] : 0;
        __syncthreads();
        sums[t] += v;
        __syncthreads();
    }
    int run = (t == 0) ? 0 : sums[t - 1];
    for (int i = 0; i < CH; ++i) {
        int idx = base + i;
        if (idx < n) { row_ptr[idx] = run; run += cnt[idx]; }
    }
    if (t == 1023) row_ptr[n] = sums[1023];
}

__global__ void fill_csr(const int* __restrict__ ei, const int* __restrict__ row_ptr,
                         int* __restrict__ cur, int* __restrict__ col) {
    int j = blockIdx.x * blockDim.x + threadIdx.x;
    if (j >= ET_EDGES) return;
    int s, d;
    if (j < N_EDGES) { s = ei[j]; d = ei[N_EDGES + j]; }
    else             { s = d = j - N_EDGES; }
    int pos = row_ptr[d] + atomicAdd(&cur[d], 1);
    col[pos] = s;
}

// ---------------- fp32 SGEMM: C[M,Nc] = A[M,K] @ B[K,Nc] ----------------

__global__ __launch_bounds__(256) void sgemm64(const float* __restrict__ A,
                                               const float* __restrict__ B,
                                               float* __restrict__ C,
                                               int M, int K, int Nc) {
    __shared__ float As[16][64];
    __shared__ float Bs[16][64];
    int bm = blockIdx.x * 64;
    int bn = blockIdx.y * 64;
    int t = threadIdx.x;
    int tr = t >> 2, tq = t & 3;
    int bkr = t >> 4, bnq = t & 15;
    int tm = (t >> 4) * 4;
    int tn = (t & 15) * 4;
    float acc[4][4] = {};
    for (int k0 = 0; k0 < K; k0 += 16) {
        int ar = bm + tr;
        float4 av = make_float4(0.f, 0.f, 0.f, 0.f);
        if (ar < M) av = *(const float4*)&A[(size_t)ar * K + k0 + tq * 4];
        As[tq * 4 + 0][tr] = av.x;
        As[tq * 4 + 1][tr] = av.y;
        As[tq * 4 + 2][tr] = av.z;
        As[tq * 4 + 3][tr] = av.w;
        float4 bv = *(const float4*)&B[(size_t)(k0 + bkr) * Nc + bn + bnq * 4];
        *(float4*)&Bs[bkr][bnq * 4] = bv;
        __syncthreads();
        #pragma unroll
        for (int k = 0; k < 16; ++k) {
            float a[4], b[4];
            *(float4*)a = *(const float4*)&As[k][tm];
            *(float4*)b = *(const float4*)&Bs[k][tn];
            #pragma unroll
            for (int i = 0; i < 4; ++i)
                #pragma unroll
                for (int j = 0; j < 4; ++j)
                    acc[i][j] = fmaf(a[i], b[j], acc[i][j]);
        }
        __syncthreads();
    }
    #pragma unroll
    for (int i = 0; i < 4; ++i) {
        int r = bm + tm + i;
        if (r < M) {
            float4 o = make_float4(acc[i][0], acc[i][1], acc[i][2], acc[i][3]);
            *(float4*)&C[(size_t)r * Nc + bn + tn] = o;
        }
    }
}

// ---------------- per-node attention coefficients (interleaved out) --------

template <int HEADS, int C>
__global__ __launch_bounds__(256) void node_alpha2(const float* __restrict__ h,
                                                   const float* __restrict__ a_src,
                                                   const float* __restrict__ a_dst,
                                                   float* __restrict__ as_,   // [N][HEADS]
                                                   float* __restrict__ ad_) { // [N][HEADS]
    constexpr int F = HEADS * C;
    constexpr int VEC = F / 64;        // 4 (F=256) or 2 (F=128)
    constexpr int LPH = C / VEC;       // lanes per head: 16 or 64
    int wid = threadIdx.x >> 6, lane = threadIdx.x & 63;
    int v = blockIdx.x * 4 + wid;
    if (v >= N_NODES) return;
    const float* hp = h + (size_t)v * F + lane * VEC;
    float ps = 0.f, pd = 0.f;
    #pragma unroll
    for (int c = 0; c < VEC; ++c) {
        float hv = hp[c];
        ps = fmaf(hv, a_src[lane * VEC + c], ps);
        pd = fmaf(hv, a_dst[lane * VEC + c], pd);
    }
    #pragma unroll
    for (int o = LPH / 2; o; o >>= 1) {
        ps += __shfl_xor(ps, o);
        pd += __shfl_xor(pd, o);
    }
    if ((lane & (LPH - 1)) == 0) {
        int head = lane / LPH;
        as_[v * HEADS + head] = ps;
        ad_[v * HEADS + head] = pd;
    }
}

// ---------------- edge weights: computed ONCE per edge --------------------
// One wave per dst node. Per edge: one float4 gather of as_[s] (all heads),
// leaky+exp, store pT[head][j] (CSR order, per-head streams); per-node
// denominators to lsum_g[v][head]. The sliced aggregate then only streams.

template <int HEADS>
__global__ __launch_bounds__(256) void edge_p(
        const float* __restrict__ as_,   // [N][HEADS]
        const float* __restrict__ ad_,   // [N][HEADS]
        const int* __restrict__ row_ptr,
        const int* __restrict__ col,
        float* __restrict__ pT,          // [HEADS][ET]
        float* __restrict__ lsum_g) {    // [N][HEADS]
    int wid = threadIdx.x >> 6, lane = threadIdx.x & 63;
    int v = blockIdx.x * 4 + wid;
    if (v >= N_NODES) return;
    int r0 = row_ptr[v], r1 = row_ptr[v + 1];
    float adh[HEADS];
    #pragma unroll
    for (int hh = 0; hh < HEADS; ++hh) adh[hh] = ad_[v * HEADS + hh];
    float ls[HEADS] = {};
    for (int base = r0; base < r1; base += 64) {
        int j = base + lane;
        bool valid = j < r1;
        int s = __builtin_nontemporal_load(&col[valid ? j : r0]);
        if (HEADS == 4) {
            float4 av = *(const float4*)&as_[s * 4];
            float ev[4] = {av.x, av.y, av.z, av.w};
            #pragma unroll
            for (int hh = 0; hh < 4; ++hh) {
                float e = ev[hh] + adh[hh];
                e = (e > 0.f) ? e : NEG_SLOPE * e;
                float p = valid ? __expf(e) : 0.f;
                ls[hh] += p;
                if (valid) __builtin_nontemporal_store(p, &pT[hh * ET_EDGES + j]);
            }
        } else {
            float e = as_[s] + adh[0];
            e = (e > 0.f) ? e : NEG_SLOPE * e;
            float p = valid ? __expf(e) : 0.f;
            ls[0] += p;
            if (valid) __builtin_nontemporal_store(p, &pT[j]);
        }
    }
    #pragma unroll
    for (int hh = 0; hh < HEADS; ++hh) {
        #pragma unroll
        for (int o = 32; o; o >>= 1) ls[hh] += __shfl_xor(ls[hh], o);
    }
    if (lane == 0) {
        #pragma unroll
        for (int hh = 0; hh < HEADS; ++hh) lsum_g[v * HEADS + hh] = ls[hh];
    }
}

// ---------------- channel-sliced aggregate (lean: weights precomputed) -----
// Wave = (dst node, 32-channel slice). slice = blockIdx.x % NSLICE keeps each
// XCD's gather working set at 20000*32*4 = 2.56 MB < 4 MiB L2. col/pT are NT
// sequential streams (don't evict the gather table). No expf / no random
// alpha gather / no reductions in staging — just (offset, weight) -> LDS.

template <int NSLICE, int SCH, int F, int HEADS, bool DO_ELU>
__global__ __launch_bounds__(256) void gat_aggregate_sliced(
        const float* __restrict__ h,      // [N, F]
        const float* __restrict__ pT,     // [HEADS][ET]
        const float* __restrict__ lsum_g, // [N][HEADS]
        const int* __restrict__ row_ptr,
        const int* __restrict__ col,
        const float* __restrict__ bias,   // [F]
        float* __restrict__ out) {        // [N, F]
    constexpr int CL = SCH / 4;           // lanes per edge (8)
    constexpr int E  = 64 / CL;           // parallel edges (8)
    constexpr int CPH = F / HEADS;        // channels per head
    __shared__ int2 s_op[4][64];          // (byte offset, weight) per staged edge
    int slice = blockIdx.x & (NSLICE - 1);
    int ng = (int)(blockIdx.x / NSLICE);
    int wid = threadIdx.x >> 6, lane = threadIdx.x & 63;
    int v = ng * 4 + wid;
    if (v >= N_NODES) return;
    int head = (slice * SCH) / CPH;       // layers 1/2: slice>>1 ; layer 3: 0
    int eg = lane / CL, cl = lane % CL;
    int r0 = row_ptr[v], r1 = row_ptr[v + 1];
    const float* pTh = pT + (size_t)head * ET_EDGES;
    float acc[4] = {};
    const char* hb = (const char*)(h + slice * SCH + cl * 4);

    for (int base = r0; base < r1; base += 64) {
        int j = base + lane;
        bool valid = j < r1;
        int s = __builtin_nontemporal_load(&col[valid ? j : r0]);
        float p = valid ? __builtin_nontemporal_load(&pTh[j]) : 0.f;
        s_op[wid][lane] = make_int2(s * (F * 4), __float_as_int(p));

        int nk = min(64, r1 - base);
        int nkg = (nk + E - 1) / E;
        for (int g = 0; g < nkg; ++g) {
            int k = g * E + eg;           // k >= nk entries have p=0
            int2 op = s_op[wid][k];
            float pk = __int_as_float(op.y);
            float4 hv = *(const float4*)(hb + op.x);
            acc[0] = fmaf(pk, hv.x, acc[0]);
            acc[1] = fmaf(pk, hv.y, acc[1]);
            acc[2] = fmaf(pk, hv.z, acc[2]);
            acc[3] = fmaf(pk, hv.w, acc[3]);
        }
    }
    // reduce acc across edge groups (lanes differing in bits >= log2(CL))
    #pragma unroll
    for (int c = 0; c < 4; ++c) {
        #pragma unroll
        for (int o = CL; o < 64; o <<= 1) acc[c] += __shfl_xor(acc[c], o);
    }
    if (eg == 0) {
        float inv = 1.f / (lsum_g[v * HEADS + head] + 1e-16f);
        int ch0 = slice * SCH + cl * 4;
        float4 ov;
        float* po = &ov.x;
        #pragma unroll
        for (int c = 0; c < 4; ++c) {
            float o = acc[c] * inv + bias[ch0 + c];
            if (DO_ELU) o = (o > 0.f) ? o : expm1f(o);
            po[c] = o;
        }
        *(float4*)&out[(size_t)v * F + ch0] = ov;
    }
}

// ---------------- global mean pool: 4-way row-split + atomic combine --------

__global__ void pool_mean4(const float* __restrict__ hout, const int* __restrict__ gstart,
                           float* __restrict__ gout) {
    int g = blockIdx.x;       // 64
    int q = blockIdx.y;       // 4 row-quarters
    int c = threadIdx.x;      // 128 channels
    int off = gstart[g], end = gstart[g + 1];
    float inv = 1.f / fmaxf((float)(end - off), 1.0f);
    float s = 0.f;
    for (int i = off + q; i < end; i += 4) s += hout[(size_t)i * 128 + c];
    atomicAdd(&gout[g * 128 + c], s * inv);
}

// ---------------- launch ----------------

static inline size_t align_up(size_t x, size_t a) { return (x + a - 1) & ~(a - 1); }

extern "C" void kernel_launch(void* const* d_in, const int* in_sizes, int n_in,
                              void* d_out, int out_size, void* d_ws, size_t ws_size,
                              hipStream_t stream) {
    const float* x   = (const float*)d_in[0];
    const int*   ei  = (const int*)d_in[1];
    const int*   bat = (const int*)d_in[2];
    const float* W1  = (const float*)d_in[3];
    const float* as1 = (const float*)d_in[4];
    const float* ad1 = (const float*)d_in[5];
    const float* b1  = (const float*)d_in[6];
    const float* W2  = (const float*)d_in[7];
    const float* as2 = (const float*)d_in[8];
    const float* ad2 = (const float*)d_in[9];
    const float* b2  = (const float*)d_in[10];
    const float* W3  = (const float*)d_in[11];
    const float* as3 = (const float*)d_in[12];
    const float* ad3 = (const float*)d_in[13];
    const float* b3  = (const float*)d_in[14];

    float* gout = (float*)d_out;                     // [G,128]
    float* hout = (float*)d_out + G_GRAPHS * 128;    // [N,128]

    char* w = (char*)d_ws;
    size_t o = 0;
    float* bufA = (float*)(w + o); o = align_up(o + (size_t)N_NODES * 256 * 4, 256);
    float* bufB = (float*)(w + o); o = align_up(o + (size_t)N_NODES * 256 * 4, 256);
    float* asv  = (float*)(w + o); o = align_up(o + (size_t)N_NODES * 4 * 4, 256);
    float* adv  = (float*)(w + o); o = align_up(o + (size_t)N_NODES * 4 * 4, 256);
    float* pT   = (float*)(w + o); o = align_up(o + (size_t)4 * ET_EDGES * 4, 256);
    float* lsum = (float*)(w + o); o = align_up(o + (size_t)N_NODES * 4 * 4, 256);
    int* row_ptr = (int*)(w + o);  o = align_up(o + (size_t)(N_NODES + 1) * 4, 256);
    int* col     = (int*)(w + o);  o = align_up(o + (size_t)ET_EDGES * 4, 256);
    int* cnt     = (int*)(w + o);  o += (size_t)N_NODES * 4;        // cnt+cur contiguous
    int* cur     = (int*)(w + o);  o = align_up(o + (size_t)N_NODES * 4, 256);
    int* gstart  = (int*)(w + o);  o = align_up(o + (size_t)(G_GRAPHS + 1) * 4, 256);

    // ---- CSR build + graph bounds ----
    hipMemsetAsync(cnt, 0, (size_t)N_NODES * 8, stream);   // cnt AND cur
    hipMemsetAsync(gout, 0, (size_t)G_GRAPHS * 128 * 4, stream);
    hist_dst<<<(ET_EDGES + 255) / 256, 256, 0, stream>>>(ei, cnt, bat, gstart);
    scan_rowptr<<<1, 1024, 0, stream>>>(cnt, row_ptr);
    fill_csr<<<(ET_EDGES + 255) / 256, 256, 0, stream>>>(ei, row_ptr, cur, col);

    dim3 g4(313, 4), g2(313, 2);
    int nb = (N_NODES + 3) / 4;   // 4 nodes per block

    // ---- layer 1: 128 -> 4x64 ----
    sgemm64<<<g4, 256, 0, stream>>>(x, W1, bufA, N_NODES, 128, 256);
    node_alpha2<4, 64><<<nb, 256, 0, stream>>>(bufA, as1, ad1, asv, adv);
    edge_p<4><<<nb, 256, 0, stream>>>(asv, adv, row_ptr, col, pT, lsum);
    gat_aggregate_sliced<8, 32, 256, 4, true><<<nb * 8, 256, 0, stream>>>(
        bufA, pT, lsum, row_ptr, col, b1, bufB);

    // ---- layer 2: 256 -> 4x64 ----
    sgemm64<<<g4, 256, 0, stream>>>(bufB, W2, bufA, N_NODES, 256, 256);
    node_alpha2<4, 64><<<nb, 256, 0, stream>>>(bufA, as2, ad2, asv, adv);
    edge_p<4><<<nb, 256, 0, stream>>>(asv, adv, row_ptr, col, pT, lsum);
    gat_aggregate_sliced<8, 32, 256, 4, true><<<nb * 8, 256, 0, stream>>>(
        bufA, pT, lsum, row_ptr, col, b2, bufB);

    // ---- layer 3: 256 -> 128 (1 head, no concat, no elu) ----
    sgemm64<<<g2, 256, 0, stream>>>(bufB, W3, bufA, N_NODES, 256, 128);
    node_alpha2<1, 128><<<nb, 256, 0, stream>>>(bufA, as3, ad3, asv, adv);
    edge_p<1><<<nb, 256, 0, stream>>>(asv, adv, row_ptr, col, pT, lsum);
    gat_aggregate_sliced<4, 32, 128, 1, false><<<nb * 4, 256, 0, stream>>>(
        bufA, pT, lsum, row_ptr, col, b3, hout);

    // ---- global mean pool ----
    pool_mean4<<<dim3(G_GRAPHS, 4), 128, 0, stream>>>(hout, gstart, gout);
}

// Round 9
// 599.747 us; speedup vs baseline: 1.1092x; 1.1092x over previous
//
#include <hip/hip_runtime.h>
#include <hip/hip_bf16.h>
#include <math.h>

#define N_NODES 20000
#define N_EDGES 640000
#define ET_EDGES (N_EDGES + N_NODES)   // with self-loops
#define G_GRAPHS 64
#define NEG_SLOPE 0.2f

// ---------------- CSR construction (+ graph bounds folded in) ----------------

__global__ void hist_dst(const int* __restrict__ ei, int* __restrict__ cnt,
                         const int* __restrict__ batch, int* __restrict__ gstart) {
    int j = blockIdx.x * blockDim.x + threadIdx.x;
    if (blockIdx.x == 0 && threadIdx.x <= G_GRAPHS) {
        int g = threadIdx.x;
        int lo = 0, hi = N_NODES;
        while (lo < hi) {              // first i with batch[i] >= g
            int mid = (lo + hi) >> 1;
            if (batch[mid] < g) lo = mid + 1; else hi = mid;
        }
        gstart[g] = lo;
    }
    if (j >= ET_EDGES) return;
    int d = (j < N_EDGES) ? ei[N_EDGES + j] : (j - N_EDGES);
    atomicAdd(&cnt[d], 1);
}

__global__ __launch_bounds__(1024) void scan_rowptr(const int* __restrict__ cnt,
                                                    int* __restrict__ row_ptr) {
    __shared__ int sums[1024];
    const int n = N_NODES;
    const int CH = (n + 1023) / 1024;   // 20
    int t = threadIdx.x;
    int base = t * CH;
    int s = 0;
    for (int i = 0; i < CH; ++i) {
        int idx = base + i;
        if (idx < n) s += cnt[idx];
    }
    sums[t] = s;
    __syncthreads();
    for (int o = 1; o < 1024; o <<= 1) {
        int v = (t >= o) ? sums[t - o] : 0;
        __syncthreads();
        sums[t] += v;
        __syncthreads();
    }
    int run = (t == 0) ? 0 : sums[t - 1];
    for (int i = 0; i < CH; ++i) {
        int idx = base + i;
        if (idx < n) { row_ptr[idx] = run; run += cnt[idx]; }
    }
    if (t == 1023) row_ptr[n] = sums[1023];
}

__global__ void fill_csr(const int* __restrict__ ei, const int* __restrict__ row_ptr,
                         int* __restrict__ cur, int* __restrict__ col) {
    int j = blockIdx.x * blockDim.x + threadIdx.x;
    if (j >= ET_EDGES) return;
    int s, d;
    if (j < N_EDGES) { s = ei[j]; d = ei[N_EDGES + j]; }
    else             { s = d = j - N_EDGES; }
    int pos = row_ptr[d] + atomicAdd(&cur[d], 1);
    col[pos] = s;
}

// ---------------- fp32 SGEMM: C[M,Nc] = A[M,K] @ B[K,Nc] ----------------

__global__ __launch_bounds__(256) void sgemm64(const float* __restrict__ A,
                                               const float* __restrict__ B,
                                               float* __restrict__ C,
                                               int M, int K, int Nc) {
    __shared__ float As[16][64];
    __shared__ float Bs[16][64];
    int bm = blockIdx.x * 64;
    int bn = blockIdx.y * 64;
    int t = threadIdx.x;
    int tr = t >> 2, tq = t & 3;
    int bkr = t >> 4, bnq = t & 15;
    int tm = (t >> 4) * 4;
    int tn = (t & 15) * 4;
    float acc[4][4] = {};
    for (int k0 = 0; k0 < K; k0 += 16) {
        int ar = bm + tr;
        float4 av = make_float4(0.f, 0.f, 0.f, 0.f);
        if (ar < M) av = *(const float4*)&A[(size_t)ar * K + k0 + tq * 4];
        As[tq * 4 + 0][tr] = av.x;
        As[tq * 4 + 1][tr] = av.y;
        As[tq * 4 + 2][tr] = av.z;
        As[tq * 4 + 3][tr] = av.w;
        float4 bv = *(const float4*)&B[(size_t)(k0 + bkr) * Nc + bn + bnq * 4];
        *(float4*)&Bs[bkr][bnq * 4] = bv;
        __syncthreads();
        #pragma unroll
        for (int k = 0; k < 16; ++k) {
            float a[4], b[4];
            *(float4*)a = *(const float4*)&As[k][tm];
            *(float4*)b = *(const float4*)&Bs[k][tn];
            #pragma unroll
            for (int i = 0; i < 4; ++i)
                #pragma unroll
                for (int j = 0; j < 4; ++j)
                    acc[i][j] = fmaf(a[i], b[j], acc[i][j]);
        }
        __syncthreads();
    }
    #pragma unroll
    for (int i = 0; i < 4; ++i) {
        int r = bm + tm + i;
        if (r < M) {
            float4 o = make_float4(acc[i][0], acc[i][1], acc[i][2], acc[i][3]);
            *(float4*)&C[(size_t)r * Nc + bn + tn] = o;
        }
    }
}

// ---------------- per-node attention coefficients (interleaved out) --------

template <int HEADS, int C>
__global__ __launch_bounds__(256) void node_alpha2(const float* __restrict__ h,
                                                   const float* __restrict__ a_src,
                                                   const float* __restrict__ a_dst,
                                                   float* __restrict__ as_,   // [N][HEADS]
                                                   float* __restrict__ ad_) { // [N][HEADS]
    constexpr int F = HEADS * C;
    constexpr int VEC = F / 64;        // 4 (F=256) or 2 (F=128)
    constexpr int LPH = C / VEC;       // lanes per head: 16 or 64
    int wid = threadIdx.x >> 6, lane = threadIdx.x & 63;
    int v = blockIdx.x * 4 + wid;
    if (v >= N_NODES) return;
    const float* hp = h + (size_t)v * F + lane * VEC;
    float ps = 0.f, pd = 0.f;
    #pragma unroll
    for (int c = 0; c < VEC; ++c) {
        float hv = hp[c];
        ps = fmaf(hv, a_src[lane * VEC + c], ps);
        pd = fmaf(hv, a_dst[lane * VEC + c], pd);
    }
    #pragma unroll
    for (int o = LPH / 2; o; o >>= 1) {
        ps += __shfl_xor(ps, o);
        pd += __shfl_xor(pd, o);
    }
    if ((lane & (LPH - 1)) == 0) {
        int head = lane / LPH;
        as_[v * HEADS + head] = ps;
        ad_[v * HEADS + head] = pd;
    }
}

// ---------------- edge weights ONCE per edge -> merged (offset, p) stream ---
// cp[head][j] packs (byte offset of h row, exp-weight) in 8 B, CSR order.
// Aggregate then needs a single sequential 8-B load per edge: no LDS staging.

template <int HEADS, int F>
__global__ __launch_bounds__(256) void edge_p(
        const float* __restrict__ as_,   // [N][HEADS]
        const float* __restrict__ ad_,   // [N][HEADS]
        const int* __restrict__ row_ptr,
        const int* __restrict__ col,
        long long* __restrict__ cp,      // [HEADS][ET] packed (off, p)
        float* __restrict__ lsum_g) {    // [N][HEADS]
    int wid = threadIdx.x >> 6, lane = threadIdx.x & 63;
    int v = blockIdx.x * 4 + wid;
    if (v >= N_NODES) return;
    int r0 = row_ptr[v], r1 = row_ptr[v + 1];
    float adh[HEADS];
    #pragma unroll
    for (int hh = 0; hh < HEADS; ++hh) adh[hh] = ad_[v * HEADS + hh];
    float ls[HEADS] = {};
    for (int base = r0; base < r1; base += 64) {
        int j = base + lane;
        bool valid = j < r1;
        int s = __builtin_nontemporal_load(&col[valid ? j : r0]);
        unsigned off = (unsigned)(s * (F * 4));
        if (HEADS == 4) {
            float4 av = *(const float4*)&as_[s * 4];
            float ev[4] = {av.x, av.y, av.z, av.w};
            #pragma unroll
            for (int hh = 0; hh < 4; ++hh) {
                float e = ev[hh] + adh[hh];
                e = (e > 0.f) ? e : NEG_SLOPE * e;
                float p = valid ? __expf(e) : 0.f;
                ls[hh] += p;
                if (valid) {
                    long long t = ((long long)__float_as_int(p) << 32) | off;
                    __builtin_nontemporal_store(t, &cp[(size_t)hh * ET_EDGES + j]);
                }
            }
        } else {
            float e = as_[s] + adh[0];
            e = (e > 0.f) ? e : NEG_SLOPE * e;
            float p = valid ? __expf(e) : 0.f;
            ls[0] += p;
            if (valid) {
                long long t = ((long long)__float_as_int(p) << 32) | off;
                __builtin_nontemporal_store(t, &cp[j]);
            }
        }
    }
    #pragma unroll
    for (int hh = 0; hh < HEADS; ++hh) {
        #pragma unroll
        for (int o = 32; o; o >>= 1) ls[hh] += __shfl_xor(ls[hh], o);
    }
    if (lane == 0) {
        #pragma unroll
        for (int hh = 0; hh < HEADS; ++hh) lsum_g[v * HEADS + hh] = ls[hh];
    }
}

// ---------------- channel-sliced aggregate, NO staging ---------------------
// Wave = (dst node, SCH-channel slice); slice = blockIdx.x % NSLICE keeps the
// per-XCD gather table at N*SCH*4 <= 2.56 MB (L2-resident). Each CL-lane
// group loads its edge's packed (off,p) word directly (address shared within
// the group -> HW-merged), then gathers float4 of h. U=4 unroll keeps 4
// independent cp->gather chains in flight. No LDS, no chunk barrier.

template <int NSLICE, int SCH, int F, int HEADS, bool DO_ELU>
__global__ __launch_bounds__(256) void gat_aggregate_ns(
        const float* __restrict__ h,      // [N, F]
        const long long* __restrict__ cp, // [HEADS][ET]
        const float* __restrict__ lsum_g, // [N][HEADS]
        const int* __restrict__ row_ptr,
        const float* __restrict__ bias,   // [F]
        float* __restrict__ out) {        // [N, F]
    constexpr int CL = SCH / 4;           // lanes per edge (8)
    constexpr int E  = 64 / CL;           // parallel edges (8)
    constexpr int CPH = F / HEADS;
    constexpr int U = 4;
    int slice = blockIdx.x % NSLICE;
    int ng = blockIdx.x / NSLICE;
    int wid = threadIdx.x >> 6, lane = threadIdx.x & 63;
    int v = ng * 4 + wid;
    if (v >= N_NODES) return;
    int head = (slice * SCH) / CPH;
    int eg = lane / CL, cl = lane % CL;
    int r0 = row_ptr[v], r1 = row_ptr[v + 1];
    int rlast = r1 - 1;
    const long long* cph = cp + (size_t)head * ET_EDGES;
    const char* hb = (const char*)h + (size_t)(slice * SCH + cl * 4) * 4;
    float acc[4] = {};

    for (int j0 = r0; j0 < r1; j0 += E * U) {
        int offs[U];
        float pv[U];
        #pragma unroll
        for (int u = 0; u < U; ++u) {
            int j = j0 + u * E + eg;
            long long t = __builtin_nontemporal_load(&cph[min(j, rlast)]);
            offs[u] = (int)(unsigned)t;
            pv[u] = (j <= rlast) ? __int_as_float((int)(t >> 32)) : 0.f;
        }
        #pragma unroll
        for (int u = 0; u < U; ++u) {
            float4 hv = *(const float4*)(hb + offs[u]);
            acc[0] = fmaf(pv[u], hv.x, acc[0]);
            acc[1] = fmaf(pv[u], hv.y, acc[1]);
            acc[2] = fmaf(pv[u], hv.z, acc[2]);
            acc[3] = fmaf(pv[u], hv.w, acc[3]);
        }
    }
    // reduce across edge groups (stride >= CL)
    #pragma unroll
    for (int c = 0; c < 4; ++c) {
        #pragma unroll
        for (int o = CL; o < 64; o <<= 1) acc[c] += __shfl_xor(acc[c], o);
    }
    if (eg == 0) {
        float inv = 1.f / (lsum_g[v * HEADS + head] + 1e-16f);
        int ch0 = slice * SCH + cl * 4;
        float4 ov;
        float* po = &ov.x;
        #pragma unroll
        for (int c = 0; c < 4; ++c) {
            float o = acc[c] * inv + bias[ch0 + c];
            if (DO_ELU) o = (o > 0.f) ? o : expm1f(o);
            po[c] = o;
        }
        *(float4*)&out[(size_t)v * F + ch0] = ov;
    }
}

// ---------------- global mean pool: 4-way row-split + atomic combine --------

__global__ void pool_mean4(const float* __restrict__ hout, const int* __restrict__ gstart,
                           float* __restrict__ gout) {
    int g = blockIdx.x;       // 64
    int q = blockIdx.y;       // 4 row-quarters
    int c = threadIdx.x;      // 128 channels
    int off = gstart[g], end = gstart[g + 1];
    float inv = 1.f / fmaxf((float)(end - off), 1.0f);
    float s = 0.f;
    for (int i = off + q; i < end; i += 4) s += hout[(size_t)i * 128 + c];
    atomicAdd(&gout[g * 128 + c], s * inv);
}

// ---------------- launch ----------------

static inline size_t align_up(size_t x, size_t a) { return (x + a - 1) & ~(a - 1); }

extern "C" void kernel_launch(void* const* d_in, const int* in_sizes, int n_in,
                              void* d_out, int out_size, void* d_ws, size_t ws_size,
                              hipStream_t stream) {
    const float* x   = (const float*)d_in[0];
    const int*   ei  = (const int*)d_in[1];
    const int*   bat = (const int*)d_in[2];
    const float* W1  = (const float*)d_in[3];
    const float* as1 = (const float*)d_in[4];
    const float* ad1 = (const float*)d_in[5];
    const float* b1  = (const float*)d_in[6];
    const float* W2  = (const float*)d_in[7];
    const float* as2 = (const float*)d_in[8];
    const float* ad2 = (const float*)d_in[9];
    const float* b2  = (const float*)d_in[10];
    const float* W3  = (const float*)d_in[11];
    const float* as3 = (const float*)d_in[12];
    const float* ad3 = (const float*)d_in[13];
    const float* b3  = (const float*)d_in[14];

    float* gout = (float*)d_out;                     // [G,128]
    float* hout = (float*)d_out + G_GRAPHS * 128;    // [N,128]

    char* w = (char*)d_ws;
    size_t o = 0;
    float* bufA = (float*)(w + o); o = align_up(o + (size_t)N_NODES * 256 * 4, 256);
    float* bufB = (float*)(w + o); o = align_up(o + (size_t)N_NODES * 256 * 4, 256);
    float* asv  = (float*)(w + o); o = align_up(o + (size_t)N_NODES * 4 * 4, 256);
    float* adv  = (float*)(w + o); o = align_up(o + (size_t)N_NODES * 4 * 4, 256);
    long long* cp = (long long*)(w + o); o = align_up(o + (size_t)4 * ET_EDGES * 8, 256);
    float* lsum = (float*)(w + o); o = align_up(o + (size_t)N_NODES * 4 * 4, 256);
    int* row_ptr = (int*)(w + o);  o = align_up(o + (size_t)(N_NODES + 1) * 4, 256);
    int* col     = (int*)(w + o);  o = align_up(o + (size_t)ET_EDGES * 4, 256);
    int* cnt     = (int*)(w + o);  o += (size_t)N_NODES * 4;        // cnt+cur contiguous
    int* cur     = (int*)(w + o);  o = align_up(o + (size_t)N_NODES * 4, 256);
    int* gstart  = (int*)(w + o);  o = align_up(o + (size_t)(G_GRAPHS + 1) * 4, 256);

    // ---- CSR build + graph bounds ----
    hipMemsetAsync(cnt, 0, (size_t)N_NODES * 8, stream);   // cnt AND cur
    hipMemsetAsync(gout, 0, (size_t)G_GRAPHS * 128 * 4, stream);
    hist_dst<<<(ET_EDGES + 255) / 256, 256, 0, stream>>>(ei, cnt, bat, gstart);
    scan_rowptr<<<1, 1024, 0, stream>>>(cnt, row_ptr);
    fill_csr<<<(ET_EDGES + 255) / 256, 256, 0, stream>>>(ei, row_ptr, cur, col);

    dim3 g4(313, 4), g2(313, 2);
    int nb = (N_NODES + 3) / 4;   // 4 nodes per block

    // ---- layer 1: 128 -> 4x64 ----
    sgemm64<<<g4, 256, 0, stream>>>(x, W1, bufA, N_NODES, 128, 256);
    node_alpha2<4, 64><<<nb, 256, 0, stream>>>(bufA, as1, ad1, asv, adv);
    edge_p<4, 256><<<nb, 256, 0, stream>>>(asv, adv, row_ptr, col, cp, lsum);
    gat_aggregate_ns<8, 32, 256, 4, true><<<nb * 8, 256, 0, stream>>>(
        bufA, cp, lsum, row_ptr, b1, bufB);

    // ---- layer 2: 256 -> 4x64 ----
    sgemm64<<<g4, 256, 0, stream>>>(bufB, W2, bufA, N_NODES, 256, 256);
    node_alpha2<4, 64><<<nb, 256, 0, stream>>>(bufA, as2, ad2, asv, adv);
    edge_p<4, 256><<<nb, 256, 0, stream>>>(asv, adv, row_ptr, col, cp, lsum);
    gat_aggregate_ns<8, 32, 256, 4, true><<<nb * 8, 256, 0, stream>>>(
        bufA, cp, lsum, row_ptr, b2, bufB);

    // ---- layer 3: 256 -> 128 (1 head, no concat, no elu) ----
    sgemm64<<<g2, 256, 0, stream>>>(bufB, W3, bufA, N_NODES, 256, 128);
    node_alpha2<1, 128><<<nb, 256, 0, stream>>>(bufA, as3, ad3, asv, adv);
    edge_p<1, 128><<<nb, 256, 0, stream>>>(asv, adv, row_ptr, col, cp, lsum);
    gat_aggregate_ns<4, 32, 128, 1, false><<<nb * 4, 256, 0, stream>>>(
        bufA, cp, lsum, row_ptr, b3, hout);

    // ---- global mean pool ----
    pool_mean4<<<dim3(G_GRAPHS, 4), 128, 0, stream>>>(hout, gstart, gout);
}

// Round 10
// 534.165 us; speedup vs baseline: 1.2454x; 1.1228x over previous
//
#include <hip/hip_runtime.h>
#include <hip/hip_bf16.h>
#include <math.h>

#define N_NODES 20000
#define N_EDGES 640000
#define ET_EDGES (N_EDGES + N_NODES)   // with self-loops
#define G_GRAPHS 64
#define NEG_SLOPE 0.2f

// ---------------- CSR construction (+ graph bounds folded in) ----------------

__global__ void hist_dst(const int* __restrict__ ei, int* __restrict__ cnt,
                         const int* __restrict__ batch, int* __restrict__ gstart) {
    int j = blockIdx.x * blockDim.x + threadIdx.x;
    if (blockIdx.x == 0 && threadIdx.x <= G_GRAPHS) {
        int g = threadIdx.x;
        int lo = 0, hi = N_NODES;
        while (lo < hi) {              // first i with batch[i] >= g
            int mid = (lo + hi) >> 1;
            if (batch[mid] < g) lo = mid + 1; else hi = mid;
        }
        gstart[g] = lo;
    }
    if (j >= ET_EDGES) return;
    int d = (j < N_EDGES) ? ei[N_EDGES + j] : (j - N_EDGES);
    atomicAdd(&cnt[d], 1);
}

__global__ __launch_bounds__(1024) void scan_rowptr(const int* __restrict__ cnt,
                                                    int* __restrict__ row_ptr) {
    __shared__ int sums[1024];
    const int n = N_NODES;
    const int CH = (n + 1023) / 1024;   // 20
    int t = threadIdx.x;
    int base = t * CH;
    int s = 0;
    for (int i = 0; i < CH; ++i) {
        int idx = base + i;
        if (idx < n) s += cnt[idx];
    }
    sums[t] = s;
    __syncthreads();
    for (int o = 1; o < 1024; o <<= 1) {
        int v = (t >= o) ? sums[t - o] : 0;
        __syncthreads();
        sums[t] += v;
        __syncthreads();
    }
    int run = (t == 0) ? 0 : sums[t - 1];
    for (int i = 0; i < CH; ++i) {
        int idx = base + i;
        if (idx < n) { row_ptr[idx] = run; run += cnt[idx]; }
    }
    if (t == 1023) row_ptr[n] = sums[1023];
}

__global__ void fill_csr(const int* __restrict__ ei, const int* __restrict__ row_ptr,
                         int* __restrict__ cur, int* __restrict__ col) {
    int j = blockIdx.x * blockDim.x + threadIdx.x;
    if (j >= ET_EDGES) return;
    int s, d;
    if (j < N_EDGES) { s = ei[j]; d = ei[N_EDGES + j]; }
    else             { s = d = j - N_EDGES; }
    int pos = row_ptr[d] + atomicAdd(&cur[d], 1);
    col[pos] = s;
}

// ---------------- fp32 SGEMM: C[M,Nc] = A[M,K] @ B[K,Nc] ----------------

__global__ __launch_bounds__(256) void sgemm64(const float* __restrict__ A,
                                               const float* __restrict__ B,
                                               float* __restrict__ C,
                                               int M, int K, int Nc) {
    __shared__ float As[16][64];
    __shared__ float Bs[16][64];
    int bm = blockIdx.x * 64;
    int bn = blockIdx.y * 64;
    int t = threadIdx.x;
    int tr = t >> 2, tq = t & 3;
    int bkr = t >> 4, bnq = t & 15;
    int tm = (t >> 4) * 4;
    int tn = (t & 15) * 4;
    float acc[4][4] = {};
    for (int k0 = 0; k0 < K; k0 += 16) {
        int ar = bm + tr;
        float4 av = make_float4(0.f, 0.f, 0.f, 0.f);
        if (ar < M) av = *(const float4*)&A[(size_t)ar * K + k0 + tq * 4];
        As[tq * 4 + 0][tr] = av.x;
        As[tq * 4 + 1][tr] = av.y;
        As[tq * 4 + 2][tr] = av.z;
        As[tq * 4 + 3][tr] = av.w;
        float4 bv = *(const float4*)&B[(size_t)(k0 + bkr) * Nc + bn + bnq * 4];
        *(float4*)&Bs[bkr][bnq * 4] = bv;
        __syncthreads();
        #pragma unroll
        for (int k = 0; k < 16; ++k) {
            float a[4], b[4];
            *(float4*)a = *(const float4*)&As[k][tm];
            *(float4*)b = *(const float4*)&Bs[k][tn];
            #pragma unroll
            for (int i = 0; i < 4; ++i)
                #pragma unroll
                for (int j = 0; j < 4; ++j)
                    acc[i][j] = fmaf(a[i], b[j], acc[i][j]);
        }
        __syncthreads();
    }
    #pragma unroll
    for (int i = 0; i < 4; ++i) {
        int r = bm + tm + i;
        if (r < M) {
            float4 o = make_float4(acc[i][0], acc[i][1], acc[i][2], acc[i][3]);
            *(float4*)&C[(size_t)r * Nc + bn + tn] = o;
        }
    }
}

// ---------------- per-node attention coefficients (interleaved out) --------

template <int HEADS, int C>
__global__ __launch_bounds__(256) void node_alpha2(const float* __restrict__ h,
                                                   const float* __restrict__ a_src,
                                                   const float* __restrict__ a_dst,
                                                   float* __restrict__ as_,   // [N][HEADS]
                                                   float* __restrict__ ad_) { // [N][HEADS]
    constexpr int F = HEADS * C;
    constexpr int VEC = F / 64;        // 4 (F=256) or 2 (F=128)
    constexpr int LPH = C / VEC;       // lanes per head: 16 or 64
    int wid = threadIdx.x >> 6, lane = threadIdx.x & 63;
    int v = blockIdx.x * 4 + wid;
    if (v >= N_NODES) return;
    const float* hp = h + (size_t)v * F + lane * VEC;
    float ps = 0.f, pd = 0.f;
    #pragma unroll
    for (int c = 0; c < VEC; ++c) {
        float hv = hp[c];
        ps = fmaf(hv, a_src[lane * VEC + c], ps);
        pd = fmaf(hv, a_dst[lane * VEC + c], pd);
    }
    #pragma unroll
    for (int o = LPH / 2; o; o >>= 1) {
        ps += __shfl_xor(ps, o);
        pd += __shfl_xor(pd, o);
    }
    if ((lane & (LPH - 1)) == 0) {
        int head = lane / LPH;
        as_[v * HEADS + head] = ps;
        ad_[v * HEADS + head] = pd;
    }
}

// ---------------- edge weights ONCE per edge -> merged (offset, p) stream ---

template <int HEADS, int F>
__global__ __launch_bounds__(256) void edge_p(
        const float* __restrict__ as_,   // [N][HEADS]
        const float* __restrict__ ad_,   // [N][HEADS]
        const int* __restrict__ row_ptr,
        const int* __restrict__ col,
        long long* __restrict__ cp,      // [HEADS][ET] packed (off, p)
        float* __restrict__ lsum_g) {    // [N][HEADS]
    int wid = threadIdx.x >> 6, lane = threadIdx.x & 63;
    int v = blockIdx.x * 4 + wid;
    if (v >= N_NODES) return;
    int r0 = row_ptr[v], r1 = row_ptr[v + 1];
    float adh[HEADS];
    #pragma unroll
    for (int hh = 0; hh < HEADS; ++hh) adh[hh] = ad_[v * HEADS + hh];
    float ls[HEADS] = {};
    for (int base = r0; base < r1; base += 64) {
        int j = base + lane;
        bool valid = j < r1;
        int s = __builtin_nontemporal_load(&col[valid ? j : r0]);
        unsigned off = (unsigned)(s * (F * 4));
        if (HEADS == 4) {
            float4 av = *(const float4*)&as_[s * 4];
            float ev[4] = {av.x, av.y, av.z, av.w};
            #pragma unroll
            for (int hh = 0; hh < 4; ++hh) {
                float e = ev[hh] + adh[hh];
                e = (e > 0.f) ? e : NEG_SLOPE * e;
                float p = valid ? __expf(e) : 0.f;
                ls[hh] += p;
                if (valid) {
                    long long t = ((long long)__float_as_int(p) << 32) | off;
                    __builtin_nontemporal_store(t, &cp[(size_t)hh * ET_EDGES + j]);
                }
            }
        } else {
            float e = as_[s] + adh[0];
            e = (e > 0.f) ? e : NEG_SLOPE * e;
            float p = valid ? __expf(e) : 0.f;
            ls[0] += p;
            if (valid) {
                long long t = ((long long)__float_as_int(p) << 32) | off;
                __builtin_nontemporal_store(t, &cp[j]);
            }
        }
    }
    #pragma unroll
    for (int hh = 0; hh < HEADS; ++hh) {
        #pragma unroll
        for (int o = 32; o; o >>= 1) ls[hh] += __shfl_xor(ls[hh], o);
    }
    if (lane == 0) {
        #pragma unroll
        for (int hh = 0; hh < HEADS; ++hh) lsum_g[v * HEADS + hh] = ls[hh];
    }
}

// ---------------- aggregate: 2 nodes/wave, 64-ch slices, no staging --------
// Wave = (node pair, 64-ch slice). Half-wave (32 lanes) per node: E=4 parallel
// edges x CL=8 lanes x 32 B (2 independent float4 gathers). U=4 unroll => 16
// edges in flight per half-wave. Waves/dispatch: 40K (L1/2), 20K (L3) vs 160K
// in round 9 — the kernel is wave-throughput bound, so fewer+fatter waves.
// slice = blockIdx.x % NSLICE -> %8 XCD affinity, 5.12 MB slice per XCD.

template <int NSLICE, int F, int HEADS, bool DO_ELU>
__global__ __launch_bounds__(256) void gat_aggregate_p2(
        const float* __restrict__ h,      // [N, F]
        const long long* __restrict__ cp, // [HEADS][ET]
        const float* __restrict__ lsum_g, // [N][HEADS]
        const int* __restrict__ row_ptr,
        const float* __restrict__ bias,   // [F]
        float* __restrict__ out) {        // [N, F]
    constexpr int SCH = 64;               // slice channels
    constexpr int CL = 8;                 // lanes per edge (per half-wave)
    constexpr int E  = 4;                 // parallel edges per half-wave
    constexpr int U  = 4;                 // unroll: 16 edges in flight
    constexpr int CPH = F / HEADS;
    int slice = blockIdx.x % NSLICE;
    int nblk = blockIdx.x / NSLICE;
    int wid = threadIdx.x >> 6, lane = threadIdx.x & 63;
    int half = lane >> 5, hl = lane & 31;
    int v = nblk * 8 + wid * 2 + half;
    if (v >= N_NODES) return;
    int head = (slice * SCH) / CPH;       // L1/2: head==slice ; L3: 0
    int eg = hl >> 3, cl = hl & 7;
    int r0 = row_ptr[v], r1 = row_ptr[v + 1];
    int rlast = r1 - 1;
    const long long* cph = cp + (size_t)head * ET_EDGES;
    const char* hb = (const char*)h + (size_t)(slice * SCH + cl * 8) * 4;
    float acc[8] = {};

    for (int j0 = r0; j0 < r1; j0 += E * U) {
        int offs[U];
        float pv[U];
        #pragma unroll
        for (int u = 0; u < U; ++u) {
            int j = j0 + u * E + eg;
            long long t = __builtin_nontemporal_load(&cph[min(j, rlast)]);
            offs[u] = (int)(unsigned)t;
            pv[u] = (j <= rlast) ? __int_as_float((int)(t >> 32)) : 0.f;
        }
        #pragma unroll
        for (int u = 0; u < U; ++u) {
            float4 h0 = *(const float4*)(hb + offs[u]);
            float4 h1 = *(const float4*)(hb + offs[u] + 16);
            acc[0] = fmaf(pv[u], h0.x, acc[0]);
            acc[1] = fmaf(pv[u], h0.y, acc[1]);
            acc[2] = fmaf(pv[u], h0.z, acc[2]);
            acc[3] = fmaf(pv[u], h0.w, acc[3]);
            acc[4] = fmaf(pv[u], h1.x, acc[4]);
            acc[5] = fmaf(pv[u], h1.y, acc[5]);
            acc[6] = fmaf(pv[u], h1.z, acc[6]);
            acc[7] = fmaf(pv[u], h1.w, acc[7]);
        }
    }
    // reduce across the 4 edge-groups (hl bits 3..4) — stays within half-wave
    #pragma unroll
    for (int c = 0; c < 8; ++c) {
        acc[c] += __shfl_xor(acc[c], 8);
        acc[c] += __shfl_xor(acc[c], 16);
    }
    if (eg == 0) {
        float inv = 1.f / (lsum_g[v * HEADS + head] + 1e-16f);
        int ch0 = slice * SCH + cl * 8;
        float4 o0, o1;
        float* po = &o0.x;
        #pragma unroll
        for (int c = 0; c < 4; ++c) {
            float o = acc[c] * inv + bias[ch0 + c];
            if (DO_ELU) o = (o > 0.f) ? o : expm1f(o);
            po[c] = o;
        }
        po = &o1.x;
        #pragma unroll
        for (int c = 0; c < 4; ++c) {
            float o = acc[4 + c] * inv + bias[ch0 + 4 + c];
            if (DO_ELU) o = (o > 0.f) ? o : expm1f(o);
            po[c] = o;
        }
        *(float4*)&out[(size_t)v * F + ch0] = o0;
        *(float4*)&out[(size_t)v * F + ch0 + 4] = o1;
    }
}

// ---------------- global mean pool: 4-way row-split + atomic combine --------

__global__ void pool_mean4(const float* __restrict__ hout, const int* __restrict__ gstart,
                           float* __restrict__ gout) {
    int g = blockIdx.x;       // 64
    int q = blockIdx.y;       // 4 row-quarters
    int c = threadIdx.x;      // 128 channels
    int off = gstart[g], end = gstart[g + 1];
    float inv = 1.f / fmaxf((float)(end - off), 1.0f);
    float s = 0.f;
    for (int i = off + q; i < end; i += 4) s += hout[(size_t)i * 128 + c];
    atomicAdd(&gout[g * 128 + c], s * inv);
}

// ---------------- launch ----------------

static inline size_t align_up(size_t x, size_t a) { return (x + a - 1) & ~(a - 1); }

extern "C" void kernel_launch(void* const* d_in, const int* in_sizes, int n_in,
                              void* d_out, int out_size, void* d_ws, size_t ws_size,
                              hipStream_t stream) {
    const float* x   = (const float*)d_in[0];
    const int*   ei  = (const int*)d_in[1];
    const int*   bat = (const int*)d_in[2];
    const float* W1  = (const float*)d_in[3];
    const float* as1 = (const float*)d_in[4];
    const float* ad1 = (const float*)d_in[5];
    const float* b1  = (const float*)d_in[6];
    const float* W2  = (const float*)d_in[7];
    const float* as2 = (const float*)d_in[8];
    const float* ad2 = (const float*)d_in[9];
    const float* b2  = (const float*)d_in[10];
    const float* W3  = (const float*)d_in[11];
    const float* as3 = (const float*)d_in[12];
    const float* ad3 = (const float*)d_in[13];
    const float* b3  = (const float*)d_in[14];

    float* gout = (float*)d_out;                     // [G,128]
    float* hout = (float*)d_out + G_GRAPHS * 128;    // [N,128]

    char* w = (char*)d_ws;
    size_t o = 0;
    float* bufA = (float*)(w + o); o = align_up(o + (size_t)N_NODES * 256 * 4, 256);
    float* bufB = (float*)(w + o); o = align_up(o + (size_t)N_NODES * 256 * 4, 256);
    float* asv  = (float*)(w + o); o = align_up(o + (size_t)N_NODES * 4 * 4, 256);
    float* adv  = (float*)(w + o); o = align_up(o + (size_t)N_NODES * 4 * 4, 256);
    long long* cp = (long long*)(w + o); o = align_up(o + (size_t)4 * ET_EDGES * 8, 256);
    float* lsum = (float*)(w + o); o = align_up(o + (size_t)N_NODES * 4 * 4, 256);
    int* row_ptr = (int*)(w + o);  o = align_up(o + (size_t)(N_NODES + 1) * 4, 256);
    int* col     = (int*)(w + o);  o = align_up(o + (size_t)ET_EDGES * 4, 256);
    int* cnt     = (int*)(w + o);  o += (size_t)N_NODES * 4;        // cnt+cur contiguous
    int* cur     = (int*)(w + o);  o = align_up(o + (size_t)N_NODES * 4, 256);
    int* gstart  = (int*)(w + o);  o = align_up(o + (size_t)(G_GRAPHS + 1) * 4, 256);

    // ---- CSR build + graph bounds ----
    hipMemsetAsync(cnt, 0, (size_t)N_NODES * 8, stream);   // cnt AND cur
    hipMemsetAsync(gout, 0, (size_t)G_GRAPHS * 128 * 4, stream);
    hist_dst<<<(ET_EDGES + 255) / 256, 256, 0, stream>>>(ei, cnt, bat, gstart);
    scan_rowptr<<<1, 1024, 0, stream>>>(cnt, row_ptr);
    fill_csr<<<(ET_EDGES + 255) / 256, 256, 0, stream>>>(ei, row_ptr, cur, col);

    dim3 g4(313, 4), g2(313, 2);
    int nb = (N_NODES + 3) / 4;    // node_alpha / edge_p blocks (4 nodes each)
    int nb8 = (N_NODES + 7) / 8;   // aggregate node-pair blocks (8 nodes each)

    // ---- layer 1: 128 -> 4x64 ----
    sgemm64<<<g4, 256, 0, stream>>>(x, W1, bufA, N_NODES, 128, 256);
    node_alpha2<4, 64><<<nb, 256, 0, stream>>>(bufA, as1, ad1, asv, adv);
    edge_p<4, 256><<<nb, 256, 0, stream>>>(asv, adv, row_ptr, col, cp, lsum);
    gat_aggregate_p2<4, 256, 4, true><<<nb8 * 4, 256, 0, stream>>>(
        bufA, cp, lsum, row_ptr, b1, bufB);

    // ---- layer 2: 256 -> 4x64 ----
    sgemm64<<<g4, 256, 0, stream>>>(bufB, W2, bufA, N_NODES, 256, 256);
    node_alpha2<4, 64><<<nb, 256, 0, stream>>>(bufA, as2, ad2, asv, adv);
    edge_p<4, 256><<<nb, 256, 0, stream>>>(asv, adv, row_ptr, col, cp, lsum);
    gat_aggregate_p2<4, 256, 4, true><<<nb8 * 4, 256, 0, stream>>>(
        bufA, cp, lsum, row_ptr, b2, bufB);

    // ---- layer 3: 256 -> 128 (1 head, no concat, no elu) ----
    sgemm64<<<g2, 256, 0, stream>>>(bufB, W3, bufA, N_NODES, 256, 128);
    node_alpha2<1, 128><<<nb, 256, 0, stream>>>(bufA, as3, ad3, asv, adv);
    edge_p<1, 128><<<nb, 256, 0, stream>>>(asv, adv, row_ptr, col, cp, lsum);
    gat_aggregate_p2<2, 128, 1, false><<<nb8 * 2, 256, 0, stream>>>(
        bufA, cp, lsum, row_ptr, b3, hout);

    // ---- global mean pool ----
    pool_mean4<<<dim3(G_GRAPHS, 4), 128, 0, stream>>>(hout, gstart, gout);
}